// Round 10
// baseline (124.164 us; speedup 1.0000x reference)
//
#include <hip/hip_runtime.h>
#include <math.h>
#include <stdint.h>

// ---------------- problem constants ----------------
#define NNODES 512
#define FEAT   128
#define NR     300
#define NC     25
#define NB     180
#define NA     360
#define RSPLIT 4
#define BCHUNK (NB / RSPLIT)   // 45
// output layout: type_dist[6] | radial_probs[300] | angular[64800] | radius | y | alpha
#define O_TYPE   0
#define O_RAD    6
#define O_ANG    306
#define O_RADIUS 65106
#define O_Y      65107
#define O_ALPHA  65108

// ---------------- workspace layout (float indices) ----------------
#define WS_KEYS   0     // 4 uints
#define WS_AKEY   16    // u64 packed angular argmax (byte 64, 8B aligned)
#define WS_ACNT   18    // u32 completion counter
#define WS_SCORES 320   // 512
#define WS_TLOG   840   // 512*6 = 3072 type logits for every node
#define WS_Q      4000  // 180*25 = 4500
#define WS_CEM    8512  // 5*7500 emb-part of coeffs per candidate type
#define WS_LRP    46016 // 300*RSPLIT partial sphere sums
#define WS_PWT    47232 // pos_wT[7500][128] transposed upper half (3.75 MB)

// K1 role split
#define R_SC  64         // focus-score MLP: 64 blocks x 8 nodes
#define R_TY  128        // type MLP for all nodes: 64 blocks x 8 nodes
#define R_PR  146        // Q extraction + keys: 18 blocks
#define R_CE  264        // CEM: 118 blocks
#define R_TR  323        // pos_w transpose: 59 blocks
#define G1_TOTAL R_TR

__constant__ int c_m_of_c[25] = {0,-1,0,1,-2,-1,0,1,2,-3,-2,-1,0,1,2,3,-4,-3,-2,-1,0,1,2,3,4};
__constant__ int c_h_cnt[9] = {5,4,3,2,1,4,3,2,1};
__constant__ int c_h_idx[9][5] = {
  {0,2,6,12,20},
  {3,7,13,21,0},
  {8,14,22,0,0},
  {15,23,0,0,0},
  {24,0,0,0,0},
  {1,5,11,19,0},
  {4,10,18,0,0},
  {9,17,0,0,0},
  {16,0,0,0,0}};

// ---------------- threefry2x32 (JAX semantics) ----------------
__device__ __forceinline__ void tf2x32(uint32_t k0, uint32_t k1, uint32_t x0, uint32_t x1,
                                       uint32_t& o0, uint32_t& o1) {
  uint32_t ks2 = k0 ^ k1 ^ 0x1BD11BDAu;
#define TF_RND(r) { x0 += x1; x1 = (x1 << r) | (x1 >> (32 - r)); x1 ^= x0; }
  x0 += k0; x1 += k1;
  TF_RND(13) TF_RND(15) TF_RND(26) TF_RND(6)
  x0 += k1; x1 += ks2 + 1u;
  TF_RND(17) TF_RND(29) TF_RND(16) TF_RND(24)
  x0 += ks2; x1 += k0 + 2u;
  TF_RND(13) TF_RND(15) TF_RND(26) TF_RND(6)
  x0 += k0; x1 += k1 + 3u;
  TF_RND(17) TF_RND(29) TF_RND(16) TF_RND(24)
  x0 += k1; x1 += ks2 + 4u;
  TF_RND(13) TF_RND(15) TF_RND(26) TF_RND(6)
  x0 += ks2; x1 += k0 + 5u;
#undef TF_RND
  o0 = x0; o1 = x1;
}

__device__ __forceinline__ float gumbel32(uint32_t k0, uint32_t k1, uint32_t lo) {
  uint32_t o0, o1; tf2x32(k0, k1, 0u, lo, o0, o1);
  uint32_t bits = o0 ^ o1;
  float u = __uint_as_float((bits >> 9) | 0x3f800000u) - 1.0f;   // [0,1)
  u = fmaxf(u, 1.1754944e-38f);                                   // minval = tiny
  return -logf(-logf(u));
}

__device__ __forceinline__ float softplusf(float s) {
  return fmaxf(s, 0.f) + log1pf(expf(-fabsf(s)));
}

// shared helper: focus argmax over scores++[0] (513) with 384 threads
__device__ __forceinline__ int focus_argmax384(const float* __restrict__ wsf,
                                               float* swv, int* swi, int t) {
  int lane = t & 63, wid = t >> 6;
  float bv = (t < NNODES) ? wsf[WS_SCORES + t] : ((t == NNODES) ? 0.f : -INFINITY);
  int bi = (t <= NNODES) ? t : (1 << 30);
  int i2 = t + 384;
  if (i2 <= NNODES) {
    float v2 = (i2 < NNODES) ? wsf[WS_SCORES + i2] : 0.f;
    if (v2 > bv) { bv = v2; bi = i2; }                 // i2>t so tie keeps smaller
  }
  for (int off = 32; off; off >>= 1) {
    float v2 = __shfl_down(bv, off); int j2 = __shfl_down(bi, off);
    if (v2 > bv || (v2 == bv && j2 < bi)) { bv = v2; bi = j2; }
  }
  if (lane == 0) { swv[wid] = bv; swi[wid] = bi; }
  __syncthreads();
  float v0 = swv[0]; int i0 = swi[0];
  for (int w = 1; w < 6; w++)
    if (swv[w] > v0 || (swv[w] == v0 && swi[w] < i0)) { v0 = swv[w]; i0 = swi[w]; }
  __syncthreads();
  return (i0 < NNODES - 1) ? i0 : (NNODES - 1);
}

// per-block coefficients for radius r: cs = xf . pos_wT rows + CEM[ti]; 384 threads
__device__ __forceinline__ void cs_for_r(const float* __restrict__ pwt,
                                         const float* __restrict__ wsf,
                                         const float* xf, float* part, float* cs,
                                         int r, int ti, int t) {
  // part[c][kk], c=t/15 (0..24), kk=t%15, k in [kk*9, min(+9,128))
  if (t < 375) {
    int c = t / 15, kk = t % 15;
    int kend = kk * 9 + 9; if (kend > 128) kend = 128;
    float acc = 0.f;
    const float* row = pwt + (size_t)(r * NC + c) * 128;
    for (int k = kk * 9; k < kend; k++) acc += xf[k] * row[k];
    part[c * 15 + kk] = acc;
  }
  __syncthreads();
  if (t < NC) {
    float a = 0.f;
#pragma unroll
    for (int kk = 0; kk < 15; kk++) a += part[t * 15 + kk];
    cs[t] = a + wsf[WS_CEM + ti * (NR * NC) + r * NC + t];
  }
  __syncthreads();
}

// ---------------- K1: scores MLP + type MLP(all nodes) + Q + CEM + transpose ----------------
__global__ __launch_bounds__(256) void k_front(const float* __restrict__ x,
    const float* __restrict__ w1, const float* __restrict__ w2, const float* __restrict__ w3,
    const float* __restrict__ w4, const float* __restrict__ w5,
    const float* __restrict__ basis, const float* __restrict__ alpha_grid,
    const float* __restrict__ tw1, const float* __restrict__ tw2, const float* __restrict__ tw3,
    const float* __restrict__ tw4, const float* __restrict__ tw5, const float* __restrict__ tw6,
    const float* __restrict__ pos_w, const float* __restrict__ type_emb,
    float* __restrict__ wsf) {
  __shared__ float SM[8256];              // 33 KB, carved per role
  int bx = blockIdx.x, t = threadIdx.x;

  if (bx < R_SC) {
    // ---- focus-score MLP: 8 nodes per block (relu x4 + head col0) ----
    float (*A)[128] = (float(*)[128])SM;
    float (*B)[128] = (float(*)[128])(SM + 1024);
    int base = bx * 8;
    for (int i = t; i < 8 * 128; i += 256) A[i >> 7][i & 127] = x[(base + (i >> 7)) * FEAT + (i & 127)];
    __syncthreads();
    int j = t & 127, h = t >> 7;
    {
      float a0 = 0, a1 = 0, a2 = 0, a3 = 0;
#pragma unroll 8
      for (int k = 0; k < 128; k++) {
        float wv = w1[k * 128 + j];
        a0 += A[h * 4 + 0][k] * wv; a1 += A[h * 4 + 1][k] * wv;
        a2 += A[h * 4 + 2][k] * wv; a3 += A[h * 4 + 3][k] * wv;
      }
      __syncthreads();
      B[h * 4 + 0][j] = fmaxf(a0, 0.f); B[h * 4 + 1][j] = fmaxf(a1, 0.f);
      B[h * 4 + 2][j] = fmaxf(a2, 0.f); B[h * 4 + 3][j] = fmaxf(a3, 0.f);
      __syncthreads();
    }
    {
      float a0 = 0, a1 = 0, a2 = 0, a3 = 0;
#pragma unroll 8
      for (int k = 0; k < 128; k++) {
        float wv = w2[k * 128 + j];
        a0 += B[h * 4 + 0][k] * wv; a1 += B[h * 4 + 1][k] * wv;
        a2 += B[h * 4 + 2][k] * wv; a3 += B[h * 4 + 3][k] * wv;
      }
      __syncthreads();
      A[h * 4 + 0][j] = fmaxf(a0, 0.f); A[h * 4 + 1][j] = fmaxf(a1, 0.f);
      A[h * 4 + 2][j] = fmaxf(a2, 0.f); A[h * 4 + 3][j] = fmaxf(a3, 0.f);
      __syncthreads();
    }
    {
      int j3 = t & 63, g = t >> 6;
      float a0 = 0, a1 = 0;
#pragma unroll 8
      for (int k = 0; k < 128; k++) {
        float wv = w3[k * 64 + j3];
        a0 += A[g * 2 + 0][k] * wv; a1 += A[g * 2 + 1][k] * wv;
      }
      __syncthreads();
      B[g * 2 + 0][j3] = fmaxf(a0, 0.f); B[g * 2 + 1][j3] = fmaxf(a1, 0.f);
      __syncthreads();
    }
    {
      int j4 = t & 15, g4 = t >> 4;
      if (g4 < 8) {
        float a0 = 0;
#pragma unroll
        for (int k = 0; k < 64; k++) a0 += B[g4][k] * w4[k * 16 + j4];
        A[g4][j4] = fmaxf(a0, 0.f);
      }
      __syncthreads();
    }
    if (t < 8) {
      float a0 = 0;
#pragma unroll
      for (int k = 0; k < 16; k++) a0 += A[t][k] * w5[k * 2 + 0];
      wsf[WS_SCORES + base + t] = a0;
    }
  } else if (bx < R_TY) {
    // ---- type MLP for 8 nodes (softplus x5 + 6-wide head), k-split-2 ----
    float* Abuf = SM;                     // 1024
    float* Bbuf = SM + 1024;              // 1024
    float* P    = SM + 2048;              // 2048 (P[ks][n*128+j])
    int base = (bx - R_SC) * 8;
    for (int i = t; i < 1024; i += 256) Abuf[i] = x[(base + (i >> 7)) * FEAT + (i & 127)];
    __syncthreads();
    const float* Ws[5] = {tw1, tw2, tw3, tw4, tw5};
    float* src = Abuf; float* dst = Bbuf;
#pragma unroll
    for (int L = 0; L < 5; L++) {
      const float* W = Ws[L];
      int j = t & 127, ks = t >> 7;
      float a0 = 0, a1 = 0, a2 = 0, a3 = 0, a4 = 0, a5 = 0, a6 = 0, a7 = 0;
#pragma unroll 8
      for (int k0 = 0; k0 < 64; k0++) {
        int k = ks * 64 + k0;
        float wv = W[k * 128 + j];
        a0 += src[0 * 128 + k] * wv; a1 += src[1 * 128 + k] * wv;
        a2 += src[2 * 128 + k] * wv; a3 += src[3 * 128 + k] * wv;
        a4 += src[4 * 128 + k] * wv; a5 += src[5 * 128 + k] * wv;
        a6 += src[6 * 128 + k] * wv; a7 += src[7 * 128 + k] * wv;
      }
      float* Pk = P + ks * 1024;
      Pk[0 * 128 + j] = a0; Pk[1 * 128 + j] = a1; Pk[2 * 128 + j] = a2; Pk[3 * 128 + j] = a3;
      Pk[4 * 128 + j] = a4; Pk[5 * 128 + j] = a5; Pk[6 * 128 + j] = a6; Pk[7 * 128 + j] = a7;
      __syncthreads();
      int half = t >> 7;
#pragma unroll
      for (int q = 0; q < 4; q++) {
        int n = half * 4 + q;
        dst[n * 128 + j] = softplusf(P[n * 128 + j] + P[1024 + n * 128 + j]);
      }
      __syncthreads();
      float* tmp = src; src = dst; dst = tmp;
    }
    if (t < 48) {
      int n = t / 6, o = t % 6;
      float a = 0.f;
      for (int j = 0; j < 128; j++) a += src[n * 128 + j] * tw6[j * 6 + o];
      wsf[WS_TLOG + (base + n) * 6 + o] = a;
    }
  } else if (bx < R_PR) {
    // ---- Q extraction + PRNG keys ----
    int p = (bx - R_TY) * 256 + t;
    if (bx == R_TY && t == 0) {
      uint32_t* wu = (uint32_t*)wsf;
      uint32_t o0, o1;
      tf2x32(0u, 42u, 0u, 0u, o0, o1); wu[WS_KEYS + 0] = o0; wu[WS_KEYS + 1] = o1; // k_r
      tf2x32(0u, 42u, 0u, 1u, o0, o1); wu[WS_KEYS + 2] = o0; wu[WS_KEYS + 3] = o1; // k_a
    }
    if (p < NB * NC) {
      int b = p / NC, c = p % NC;
      int m = c_m_of_c[c];
      float q;
      if (m >= 0) {
        q = basis[(b * NA + 0) * NC + c];                 // cos(0)=1
      } else {
        float a10 = alpha_grid[10];
        q = basis[(b * NA + 10) * NC + c] / sinf((float)(-m) * a10);
      }
      wsf[WS_Q + p] = q;
    }
  } else if (bx < R_CE) {
    // ---- CEM: emb-part of coeffs for all 5 candidate types ----
    float* es = SM;                       // 640
    float* part = SM + 640;               // 5*4*64 = 1280 : part[ti*256 + kc*64 + oL]
    int cb = bx - R_PR;
    for (int i = t; i < 640; i += 256) es[i] = type_emb[i];
    __syncthreads();
    int oL = t & 63, kc = t >> 6;
    int o = cb * 64 + oL;
    float e0 = 0, e1 = 0, e2 = 0, e3 = 0, e4 = 0;
    if (o < NR * NC) {
#pragma unroll 8
      for (int k8 = 0; k8 < 32; k8++) {
        int k = kc * 32 + k8;
        float wv = pos_w[(128 + k) * (NR * NC) + o];
        e0 += es[k] * wv;        e1 += es[128 + k] * wv;
        e2 += es[256 + k] * wv;  e3 += es[384 + k] * wv;
        e4 += es[512 + k] * wv;
      }
    }
    part[0 * 256 + kc * 64 + oL] = e0; part[1 * 256 + kc * 64 + oL] = e1;
    part[2 * 256 + kc * 64 + oL] = e2; part[3 * 256 + kc * 64 + oL] = e3;
    part[4 * 256 + kc * 64 + oL] = e4;
    __syncthreads();
    if (t < 64) {
      int oo = cb * 64 + t;
      if (oo < NR * NC) {
#pragma unroll
        for (int ti = 0; ti < 5; ti++) {
          float s = part[ti * 256 + 0 * 64 + t] + part[ti * 256 + 1 * 64 + t]
                  + part[ti * 256 + 2 * 64 + t] + part[ti * 256 + 3 * 64 + t];
          wsf[WS_CEM + ti * (NR * NC) + oo] = s;
        }
      }
    }
  } else {
    // ---- transpose upper pos_w rows 0..127 -> pos_wT[7500][128] ----
    float (*tile)[129] = (float(*)[129])SM;   // 64 x 129
    float* pwt = wsf + WS_PWT;
    int cb = bx - R_CE;
    int o0 = cb * 128;
#pragma unroll
    for (int h = 0; h < 2; h++) {
      int kb = h * 64;
      __syncthreads();
      int col = t & 127, rbase = t >> 7;
      for (int rep = 0; rep < 32; rep++) {
        int row = rbase + rep * 2;
        tile[row][col] = (o0 + col < NR * NC) ? pos_w[(kb + row) * (NR * NC) + o0 + col] : 0.f;
      }
      __syncthreads();
      int kk = t & 63, obase = t >> 6;
      for (int rep = 0; rep < 32; rep++) {
        int op = obase + rep * 4;
        if (o0 + op < NR * NC) pwt[(size_t)(o0 + op) * 128 + kb + kk] = tile[kk][op];
      }
    }
  }
}

// ---------------- K2: per-(radius, beta-chunk) sphere sum, self-sufficient ----------------
__global__ __launch_bounds__(384) void k_lse(const float* __restrict__ x,
    const float* __restrict__ qw, const float* __restrict__ alpha_grid,
    float* __restrict__ out, float* __restrict__ wsf) {
  __shared__ float xf[128];
  __shared__ float part[375];
  __shared__ float cs[NC];
  __shared__ float4 Hs4[BCHUNK * 3];
  __shared__ float wred[6]; __shared__ int wri[6];
  __shared__ int ti_sh;
  int bx = blockIdx.x, t = threadIdx.x;
  int r = bx >> 2, s = bx & 3, b0 = s * BCHUNK;
  float* Hs = (float*)Hs4;

  int focus = focus_argmax384(wsf, wred, wri, t);
  if (t < 128) xf[t] = x[focus * FEAT + t];
  if (t == 0) {
    const float* tl = wsf + WS_TLOG + focus * 6;
    float M = tl[0]; int am = 0;
    for (int i = 1; i < 6; i++) if (tl[i] > M) { M = tl[i]; am = i; }
    ti_sh = (am < 4) ? am : 4;
    if (bx == 0) {
      // type_dist softmax output + reset angular-argmax slots
      float e[6], S = 0.f;
      for (int i = 0; i < 6; i++) { e[i] = expf(tl[i] - M); S += e[i]; }
      for (int i = 0; i < 6; i++) out[O_TYPE + i] = e[i] / S;
      *(unsigned long long*)(wsf + WS_AKEY) = 0ULL;
      *(unsigned int*)(wsf + WS_ACNT) = 0u;
    }
  }
  __syncthreads();
  cs_for_r(wsf + WS_PWT, wsf, xf, part, cs, r, ti_sh, t);

  const float LOGM = -4.0482054576f;      // log(2*pi/360)
  for (int p = t; p < BCHUNK * 9; p += 384) {
    int b = p / 9, jj = p % 9;
    int bg = b0 + b;
    int n = c_h_cnt[jj];
    float acc = 0.f;
    for (int q = 0; q < n; q++) { int c = c_h_idx[jj][q]; acc += cs[c] * wsf[WS_Q + bg * NC + c]; }
    if (jj == 0) acc += logf(qw[bg]) + LOGM;
    Hs[b * 12 + jj] = acc;
  }
  __syncthreads();
  float c1 = 0, c2 = 0, c3 = 0, c4 = 0, s1 = 0, s2 = 0, s3 = 0, s4 = 0;
  bool act = t < NA;
  if (act) {
    float al = alpha_grid[t];
    sincosf(al, &s1, &c1);
    sincosf(2.f * al, &s2, &c2);
    sincosf(3.f * al, &s3, &c3);
    sincosf(4.f * al, &s4, &c4);
  }
  float acc = 0.f;
#pragma unroll 5
  for (int b = 0; b < BCHUNK; b++) {
    float4 h0 = Hs4[b * 3 + 0], h1 = Hs4[b * 3 + 1], h2 = Hs4[b * 3 + 2];
    float f = h0.x + h0.y * c1 + h0.z * c2 + h0.w * c3 + h1.x * c4
            + h1.y * s1 + h1.z * s2 + h1.w * s3 + h2.x * s4;
    acc += act ? __expf(f) : 0.f;
  }
  for (int off = 32; off; off >>= 1) acc += __shfl_down(acc, off);
  int wid = t >> 6, lane = t & 63;
  __syncthreads();
  if (lane == 0) wred[wid] = acc;
  __syncthreads();
  if (t == 0) {
    float ss = 0.f;
    for (int w = 0; w < 6; w++) ss += wred[w];
    wsf[WS_LRP + bx] = ss;
  }
}

// ---------------- K3: radial sample (redundant) + angular + atomic finish ----------------
__global__ __launch_bounds__(384) void k_ang(const float* __restrict__ x,
    const float* __restrict__ qw, const float* __restrict__ alpha_grid,
    const float* __restrict__ y_grid,
    float* __restrict__ out, float* __restrict__ wsf) {
  __shared__ float xf[128];
  __shared__ float part[375];
  __shared__ float cs[NC];
  __shared__ float hsh[12];
  __shared__ float fss[NR];
  __shared__ float wred[6]; __shared__ int wri[6];
  __shared__ float S_sh; __shared__ int r_sh, ti_sh;
  int b = blockIdx.x, t = threadIdx.x;
  int lane = t & 63, wid = t >> 6;
  const uint32_t* wu = (const uint32_t*)wsf;
  uint32_t kr0 = wu[WS_KEYS + 0], kr1 = wu[WS_KEYS + 1];
  uint32_t ka0 = wu[WS_KEYS + 2], ka1 = wu[WS_KEYS + 3];

  int focus = focus_argmax384(wsf, wred, wri, t);
  if (t < 128) xf[t] = x[focus * FEAT + t];
  if (t == 0) {
    const float* tl = wsf + WS_TLOG + focus * 6;
    float M = tl[0]; int am = 0;
    for (int i = 1; i < 6; i++) if (tl[i] > M) { M = tl[i]; am = i; }
    ti_sh = (am < 4) ? am : 4;
  }
  __syncthreads();
  int ti = ti_sh;

  // ---- radial: every block computes the same sample (deterministic) ----
  float sv = 0.f, lr = -INFINITY;
  if (t < NR) {
    sv = wsf[WS_LRP + 4 * t] + wsf[WS_LRP + 4 * t + 1]
       + wsf[WS_LRP + 4 * t + 2] + wsf[WS_LRP + 4 * t + 3];
    fss[t] = sv;
    lr = logf(sv);
  }
  float ss = sv;
  for (int off = 32; off; off >>= 1) ss += __shfl_down(ss, off);
  if (lane == 0) wred[wid] = ss;
  __syncthreads();
  if (t == 0) {
    float S = 0.f;
    for (int w = 0; w < 6; w++) S += wred[w];
    S_sh = S;
  }
  __syncthreads();
  if (b == 0 && t < NR) out[O_RAD + t] = sv / S_sh;
  float v = (t < NR) ? lr + gumbel32(kr0, kr1, (uint32_t)t) : -INFINITY;
  int bi = (t < NR) ? t : (1 << 30);
  for (int off = 32; off; off >>= 1) {
    float v2 = __shfl_down(v, off); int i2 = __shfl_down(bi, off);
    if (v2 > v || (v2 == v && i2 < bi)) { v = v2; bi = i2; }
  }
  __syncthreads();
  if (lane == 0) { wred[wid] = v; wri[wid] = bi; }
  __syncthreads();
  if (t == 0) {
    float v0 = wred[0]; int i0 = wri[0];
    for (int w = 1; w < 6; w++)
      if (wred[w] > v0 || (wred[w] == v0 && wri[w] < i0)) { v0 = wred[w]; i0 = wri[w]; }
    r_sh = i0;
    if (b == 0) out[O_RADIUS] = (float)(i0 + 1) * 0.05f;
  }
  __syncthreads();
  int r = r_sh;
  float invZ = 1.0f / fss[r];             // Z_angular = exp(log_radial[r])

  // ---- coefficients + H for this beta ----
  cs_for_r(wsf + WS_PWT, wsf, xf, part, cs, r, ti, t);
  if (t < 9) {
    int n = c_h_cnt[t];
    float acc = 0.f;
    for (int q = 0; q < n; q++) { int c = c_h_idx[t][q]; acc += cs[c] * wsf[WS_Q + b * NC + c]; }
    hsh[t] = acc;                         // no log-measure folded
  }
  __syncthreads();
  const float MEAS = 0.01745329252f;      // 2*pi/360
  float elm = qw[b] * MEAS;               // exp(log_meas[b]) exactly
  float lm = logf(elm);
  float va = -INFINITY; int idx = (t < NA) ? b * NA + t : (1 << 30);
  if (t < NA) {
    float al = alpha_grid[t];
    float s1, c1, s2, c2, s3, c3, s4, c4;
    sincosf(al, &s1, &c1); sincosf(2.f * al, &s2, &c2);
    sincosf(3.f * al, &s3, &c3); sincosf(4.f * al, &s4, &c4);
    float f = hsh[0] + hsh[1] * c1 + hsh[2] * c2 + hsh[3] * c3 + hsh[4] * c4
            + hsh[5] * s1 + hsh[6] * s2 + hsh[7] * s3 + hsh[8] * s4;
    out[O_ANG + idx] = __expf(f) * invZ;  // angular_dist = exp(fr - logZr)
    va = f + lm + gumbel32(ka0, ka1, (uint32_t)idx);
  }
  for (int off = 32; off; off >>= 1) {
    float v2 = __shfl_down(va, off); int i2 = __shfl_down(idx, off);
    if (v2 > va || (v2 == va && i2 < idx)) { va = v2; idx = i2; }
  }
  __syncthreads();
  if (lane == 0) { wred[wid] = va; wri[wid] = idx; }
  __syncthreads();
  if (t == 0) {
    float v0 = wred[0]; int i0 = wri[0];
    for (int w = 1; w < 6; w++)
      if (wred[w] > v0 || (wred[w] == v0 && wri[w] < i0)) { v0 = wred[w]; i0 = wri[w]; }
    // pack (value, index) into ordered u64: larger value wins; tie -> smaller index
    uint32_t u = __float_as_uint(v0);
    uint32_t ordv = (u & 0x80000000u) ? ~u : (u | 0x80000000u);
    unsigned long long key = ((unsigned long long)ordv << 32)
                           | (unsigned long long)(0xFFFFFFFFu - (uint32_t)i0);
    atomicMax((unsigned long long*)(wsf + WS_AKEY), key);
    __threadfence();
    unsigned int old = atomicAdd((unsigned int*)(wsf + WS_ACNT), 1u);
    if (old == NB - 1) {
      __threadfence();
      unsigned long long kk = atomicMax((unsigned long long*)(wsf + WS_AKEY), 0ULL);
      uint32_t gidx = 0xFFFFFFFFu - (uint32_t)(kk & 0xFFFFFFFFull);
      int yi = (int)(gidx / NA), ai = (int)(gidx % NA);
      out[O_Y] = y_grid[yi];
      out[O_ALPHA] = alpha_grid[ai];
    }
  }
}

// ---------------- launch ----------------
extern "C" void kernel_launch(void* const* d_in, const int* in_sizes, int n_in,
                              void* d_out, int out_size, void* d_ws, size_t ws_size,
                              hipStream_t stream) {
  const float* x          = (const float*)d_in[0];
  const float* fw1        = (const float*)d_in[1];
  const float* fw2        = (const float*)d_in[2];
  const float* fw3        = (const float*)d_in[3];
  const float* fw4        = (const float*)d_in[4];
  const float* fw5        = (const float*)d_in[5];
  const float* tw1        = (const float*)d_in[6];
  const float* tw2        = (const float*)d_in[7];
  const float* tw3        = (const float*)d_in[8];
  const float* tw4        = (const float*)d_in[9];
  const float* tw5        = (const float*)d_in[10];
  const float* tw6        = (const float*)d_in[11];
  const float* pos_w      = (const float*)d_in[12];
  const float* type_emb   = (const float*)d_in[13];
  const float* basis      = (const float*)d_in[14];
  const float* qw         = (const float*)d_in[15];
  const float* y_grid     = (const float*)d_in[16];
  const float* alpha_grid = (const float*)d_in[17];
  (void)in_sizes; (void)n_in; (void)out_size; (void)ws_size;
  float* out = (float*)d_out;
  float* wsf = (float*)d_ws;

  k_front<<<G1_TOTAL, 256, 0, stream>>>(x, fw1, fw2, fw3, fw4, fw5, basis, alpha_grid,
                                        tw1, tw2, tw3, tw4, tw5, tw6, pos_w, type_emb, wsf);
  k_lse<<<NR * RSPLIT, 384, 0, stream>>>(x, qw, alpha_grid, out, wsf);
  k_ang<<<NB, 384, 0, stream>>>(x, qw, alpha_grid, y_grid, out, wsf);
}

// Round 11
// 56.681 us; speedup vs baseline: 2.1906x; 2.1906x over previous
//
#include <hip/hip_runtime.h>
#include <math.h>
#include <stdint.h>

// ---------------- problem constants ----------------
#define NNODES 512
#define FEAT   128
#define NR     300
#define NC     25
#define NB     180
#define NA     360
#define RSPLIT 4
#define BCHUNK (NB / RSPLIT)   // 45
// output layout: type_dist[6] | radial_probs[300] | angular[64800] | radius | y | alpha
#define O_TYPE   0
#define O_RAD    6
#define O_ANG    306
#define O_RADIUS 65106
#define O_Y      65107
#define O_ALPHA  65108

// ---------------- workspace layout (float indices) ----------------
#define WS_KEYS   0     // 4 uints: k_r(2), k_a(2)
#define WS_TYPEI  5     // int
#define WS_DEAD   8     // dead slot for prefetch dummy-use
#define WS_AKEY   16    // u64 packed (ord(v)<<32 | ~idx) angular argmax (byte 64, 8B aligned)
#define WS_ACNT   18    // u32 completion counter
#define WS_SCORES 320   // 512
#define WS_Q      1664  // 180*25 = 4500
#define WS_CXF    6176  // 7500   xf-part of coeffs
#define WS_CEM    13696 // 5*7500 emb-part of coeffs per candidate type
#define WS_LRP    51200 // 300*RSPLIT partial sphere sums

// grid split for k_front
#define G1_MLP   64                      // 64 blocks x 8 nodes
#define G1_PREP  18                      // Q extraction (18*256 >= 4500)
#define G1_PFT   21                      // type-weight prefetch
#define G1_PFP   240                     // pos_w prefetch
#define G1_TOTAL (G1_MLP + G1_PREP + G1_PFT + G1_PFP)   // 343

__constant__ int c_m_of_c[25] = {0,-1,0,1,-2,-1,0,1,2,-3,-2,-1,0,1,2,3,-4,-3,-2,-1,0,1,2,3,4};
__constant__ int c_h_cnt[9] = {5,4,3,2,1,4,3,2,1};
__constant__ int c_h_idx[9][5] = {
  {0,2,6,12,20},
  {3,7,13,21,0},
  {8,14,22,0,0},
  {15,23,0,0,0},
  {24,0,0,0,0},
  {1,5,11,19,0},
  {4,10,18,0,0},
  {9,17,0,0,0},
  {16,0,0,0,0}};

// ---------------- threefry2x32 (JAX semantics) ----------------
__device__ __forceinline__ void tf2x32(uint32_t k0, uint32_t k1, uint32_t x0, uint32_t x1,
                                       uint32_t& o0, uint32_t& o1) {
  uint32_t ks2 = k0 ^ k1 ^ 0x1BD11BDAu;
#define TF_RND(r) { x0 += x1; x1 = (x1 << r) | (x1 >> (32 - r)); x1 ^= x0; }
  x0 += k0; x1 += k1;
  TF_RND(13) TF_RND(15) TF_RND(26) TF_RND(6)
  x0 += k1; x1 += ks2 + 1u;
  TF_RND(17) TF_RND(29) TF_RND(16) TF_RND(24)
  x0 += ks2; x1 += k0 + 2u;
  TF_RND(13) TF_RND(15) TF_RND(26) TF_RND(6)
  x0 += k0; x1 += k1 + 3u;
  TF_RND(17) TF_RND(29) TF_RND(16) TF_RND(24)
  x0 += k1; x1 += ks2 + 4u;
  TF_RND(13) TF_RND(15) TF_RND(26) TF_RND(6)
  x0 += ks2; x1 += k0 + 5u;
#undef TF_RND
  o0 = x0; o1 = x1;
}

__device__ __forceinline__ float gumbel32(uint32_t k0, uint32_t k1, uint32_t lo) {
  uint32_t o0, o1; tf2x32(k0, k1, 0u, lo, o0, o1);
  uint32_t bits = o0 ^ o1;
  float u = __uint_as_float((bits >> 9) | 0x3f800000u) - 1.0f;   // [0,1)
  u = fmaxf(u, 1.1754944e-38f);                                   // minval = tiny
  return -logf(-logf(u));
}

__device__ __forceinline__ float softplusf(float s) {
  return fmaxf(s, 0.f) + log1pf(expf(-fabsf(s)));
}

// ---------------- K1: focus MLP + Q-prep + tw prefetch + pos_w prefetch ----------------
__global__ __launch_bounds__(256) void k_front(const float* __restrict__ x,
    const float* __restrict__ w1, const float* __restrict__ w2, const float* __restrict__ w3,
    const float* __restrict__ w4, const float* __restrict__ w5,
    const float* __restrict__ basis, const float* __restrict__ alpha_grid,
    const float* __restrict__ tw1, const float* __restrict__ tw2, const float* __restrict__ tw3,
    const float* __restrict__ tw4, const float* __restrict__ tw5, const float* __restrict__ tw6,
    const float* __restrict__ pos_w,
    float* __restrict__ wsf) {
  __shared__ float A[8][128];
  __shared__ float B[8][128];
  int bx = blockIdx.x, t = threadIdx.x;

  if (bx < G1_MLP) {
    // ---- focus MLP: 8 nodes per block ----
    int base = bx * 8;
    for (int i = t; i < 8 * 128; i += 256) A[i >> 7][i & 127] = x[(base + (i >> 7)) * FEAT + (i & 127)];
    __syncthreads();
    int j = t & 127, h = t >> 7;          // h in {0,1}: nodes h*4..h*4+3
    {
      float a0 = 0, a1 = 0, a2 = 0, a3 = 0;
#pragma unroll 8
      for (int k = 0; k < 128; k++) {
        float wv = w1[k * 128 + j];
        a0 += A[h * 4 + 0][k] * wv; a1 += A[h * 4 + 1][k] * wv;
        a2 += A[h * 4 + 2][k] * wv; a3 += A[h * 4 + 3][k] * wv;
      }
      __syncthreads();
      B[h * 4 + 0][j] = fmaxf(a0, 0.f); B[h * 4 + 1][j] = fmaxf(a1, 0.f);
      B[h * 4 + 2][j] = fmaxf(a2, 0.f); B[h * 4 + 3][j] = fmaxf(a3, 0.f);
      __syncthreads();
    }
    {
      float a0 = 0, a1 = 0, a2 = 0, a3 = 0;
#pragma unroll 8
      for (int k = 0; k < 128; k++) {
        float wv = w2[k * 128 + j];
        a0 += B[h * 4 + 0][k] * wv; a1 += B[h * 4 + 1][k] * wv;
        a2 += B[h * 4 + 2][k] * wv; a3 += B[h * 4 + 3][k] * wv;
      }
      __syncthreads();
      A[h * 4 + 0][j] = fmaxf(a0, 0.f); A[h * 4 + 1][j] = fmaxf(a1, 0.f);
      A[h * 4 + 2][j] = fmaxf(a2, 0.f); A[h * 4 + 3][j] = fmaxf(a3, 0.f);
      __syncthreads();
    }
    {
      int j3 = t & 63, g = t >> 6;        // g in 0..3, nodes g*2, g*2+1
      float a0 = 0, a1 = 0;
#pragma unroll 8
      for (int k = 0; k < 128; k++) {
        float wv = w3[k * 64 + j3];
        a0 += A[g * 2 + 0][k] * wv; a1 += A[g * 2 + 1][k] * wv;
      }
      __syncthreads();
      B[g * 2 + 0][j3] = fmaxf(a0, 0.f); B[g * 2 + 1][j3] = fmaxf(a1, 0.f);
      __syncthreads();
    }
    {
      int j4 = t & 15, g4 = t >> 4;       // g4<8 -> node g4
      if (g4 < 8) {
        float a0 = 0;
#pragma unroll
        for (int k = 0; k < 64; k++) a0 += B[g4][k] * w4[k * 16 + j4];
        A[g4][j4] = fmaxf(a0, 0.f);
      }
      __syncthreads();
    }
    if (t < 8) {
      float a0 = 0;
#pragma unroll
      for (int k = 0; k < 16; k++) a0 += A[t][k] * w5[k * 2 + 0];
      wsf[WS_SCORES + base + t] = a0;
    }
  } else if (bx < G1_MLP + G1_PREP) {
    // ---- prep role: Q extraction + PRNG keys ----
    int p = (bx - G1_MLP) * 256 + t;
    if (bx == G1_MLP && t == 0) {
      uint32_t* wu = (uint32_t*)wsf;
      uint32_t o0, o1;
      tf2x32(0u, 42u, 0u, 0u, o0, o1); wu[WS_KEYS + 0] = o0; wu[WS_KEYS + 1] = o1; // k_r
      tf2x32(0u, 42u, 0u, 1u, o0, o1); wu[WS_KEYS + 2] = o0; wu[WS_KEYS + 3] = o1; // k_a
    }
    if (p < NB * NC) {
      int b = p / NC, c = p % NC;
      int m = c_m_of_c[c];
      float q;
      if (m >= 0) {
        q = basis[(b * NA + 0) * NC + c];                 // cos(0)=1
      } else {
        float a10 = alpha_grid[10];
        q = basis[(b * NA + 10) * NC + c] / sinf((float)(-m) * a10);
      }
      wsf[WS_Q + p] = q;
    }
  } else if (bx < G1_MLP + G1_PREP + G1_PFT) {
    // ---- type-weight prefetch into caches ----
    const float4* mats[5] = {(const float4*)tw1, (const float4*)tw2, (const float4*)tw3,
                             (const float4*)tw4, (const float4*)tw5};
    int lid = (bx - (G1_MLP + G1_PREP)) * 256 + t;
    float acc = 0.f;
    for (int vi = lid; vi < 20672; vi += G1_PFT * 256) {
      int mi = vi >> 12;
      float4 v;
      if (mi < 5) v = mats[mi][vi & 4095];
      else        v = ((const float4*)tw6)[vi - 20480];
      acc += v.x + v.y + v.z + v.w;
    }
    if (acc == -1.2345678e30f) wsf[WS_DEAD] = acc;   // never true; defeats DCE
  } else {
    // ---- pos_w prefetch into caches ----
    int lid = (bx - (G1_MLP + G1_PREP + G1_PFT)) * 256 + t;
    const float4* p4 = (const float4*)pos_w;
    float acc = 0.f;
    for (int i = lid; i < NR * NC * 256 / 4; i += G1_PFP * 256) {
      float4 v = p4[i];
      acc += v.x + v.y + v.z + v.w;
    }
    if (acc == -1.2345678e30f) wsf[WS_DEAD] = acc;
  }
}

// ---------------- K2: block 0 = type MLP; blocks 1..118 = coeff parts (xf + 5 emb) ----------------
__global__ __launch_bounds__(1024) void k_mid(const float* __restrict__ x,
    const float* __restrict__ w1, const float* __restrict__ w2, const float* __restrict__ w3,
    const float* __restrict__ w4, const float* __restrict__ w5, const float* __restrict__ w6,
    const float* __restrict__ type_emb, const float* __restrict__ pos_w,
    float* __restrict__ out, float* __restrict__ wsf) {
  __shared__ float wrv[16]; __shared__ int wri[16];
  __shared__ int f_sh;
  int t = threadIdx.x;
  int lane = t & 63, wid = t >> 6;
  // ---- every block: focus argmax over 513 (scores ++ [0]) ----
  float bv = -INFINITY; int bi = 1 << 30;
  if (t < NNODES + 1) { bv = (t < NNODES) ? wsf[WS_SCORES + t] : 0.f; bi = t; }
  for (int off = 32; off; off >>= 1) {
    float v2 = __shfl_down(bv, off); int i2 = __shfl_down(bi, off);
    if (v2 > bv || (v2 == bv && i2 < bi)) { bv = v2; bi = i2; }
  }
  if (lane == 0) { wrv[wid] = bv; wri[wid] = bi; }
  __syncthreads();
  if (t == 0) {
    float v0 = wrv[0]; int i0 = wri[0];
    for (int w = 1; w < 16; w++)
      if (wrv[w] > v0 || (wrv[w] == v0 && wri[w] < i0)) { v0 = wrv[w]; i0 = wri[w]; }
    f_sh = (i0 < NNODES - 1) ? i0 : (NNODES - 1);
  }
  __syncthreads();
  int focus = f_sh;

  if (blockIdx.x == 0) {
    // ---- type MLP (softplus), K split 8 ways ----
    __shared__ float src[128];
    __shared__ float partial[8][128];
    if (t < 128) src[t] = x[focus * FEAT + t];
    __syncthreads();
    const float* Ws[5] = {w1, w2, w3, w4, w5};
#pragma unroll
    for (int L = 0; L < 5; L++) {
      const float* W = Ws[L];
      int j = t & 127, kc = t >> 7;
      float acc = 0.f;
#pragma unroll
      for (int k = 0; k < 16; k++) acc += src[kc * 16 + k] * W[(kc * 16 + k) * 128 + j];
      partial[kc][j] = acc;
      __syncthreads();
      if (t < 128) {
        float s = 0.f;
#pragma unroll
        for (int q = 0; q < 8; q++) s += partial[q][t];
        src[t] = softplusf(s);
      }
      __syncthreads();
    }
    float prod = 0.f;
    if (t < 768) { int o = t >> 7, j = t & 127; prod = src[j] * w6[j * 6 + o]; }
    for (int off = 32; off; off >>= 1) prod += __shfl_down(prod, off);
    if (t < 768 && lane == 0) wrv[wid] = prod;    // wid = 2*o (+1)
    __syncthreads();
    if (t == 0) {
      float lg[6];
      for (int o = 0; o < 6; o++) lg[o] = wrv[2 * o] + wrv[2 * o + 1];
      float M = lg[0]; int am = 0;
      for (int i = 1; i < 6; i++) if (lg[i] > M) { M = lg[i]; am = i; }
      float e[6], S = 0.f;
      for (int i = 0; i < 6; i++) { e[i] = expf(lg[i] - M); S += e[i]; }
      for (int i = 0; i < 6; i++) out[O_TYPE + i] = e[i] / S;
      ((int*)wsf)[WS_TYPEI] = (am < 4) ? am : 4;
    }
  } else {
    // ---- coefficient parts for 64 outputs ----
    __shared__ float xf[128];
    __shared__ float es[5 * 128];
    __shared__ float px[16][64];
    __shared__ float pe[5][16][64];
    if (t < 128) xf[t] = x[focus * FEAT + t];
    if (t < 640) es[t] = type_emb[t];
    __syncthreads();
    int oL = t & 63, kc = t >> 6;           // kc in 0..15
    int o = (blockIdx.x - 1) * 64 + oL;
    bool valid = o < NR * NC;
    float ax = 0.f, e0 = 0.f, e1 = 0.f, e2 = 0.f, e3 = 0.f, e4 = 0.f;
    if (valid) {
#pragma unroll
      for (int k8 = 0; k8 < 8; k8++) {
        int k = kc * 8 + k8;
        float w0 = pos_w[k * (NR * NC) + o];
        ax += xf[k] * w0;
        float wv = pos_w[(128 + k) * (NR * NC) + o];
        e0 += es[k] * wv;        e1 += es[128 + k] * wv;
        e2 += es[256 + k] * wv;  e3 += es[384 + k] * wv;
        e4 += es[512 + k] * wv;
      }
    }
    px[kc][oL] = ax;
    pe[0][kc][oL] = e0; pe[1][kc][oL] = e1; pe[2][kc][oL] = e2;
    pe[3][kc][oL] = e3; pe[4][kc][oL] = e4;
    __syncthreads();
    if (t < 64) {
      int oo = (blockIdx.x - 1) * 64 + t;
      if (oo < NR * NC) {
        float s = 0.f;
#pragma unroll
        for (int q = 0; q < 16; q++) s += px[q][t];
        wsf[WS_CXF + oo] = s;
#pragma unroll
        for (int ti = 0; ti < 5; ti++) {
          float s2 = 0.f;
#pragma unroll
          for (int q = 0; q < 16; q++) s2 += pe[ti][q][t];
          wsf[WS_CEM + ti * (NR * NC) + oo] = s2;
        }
      }
    }
  }
}

// ---------------- K3: per-(radius, beta-chunk) partial sphere sum ----------------
__global__ __launch_bounds__(384) void k_radial_lse(const float* __restrict__ qw,
    const float* __restrict__ alpha_grid, float* __restrict__ wsf) {
  __shared__ float4 Hs4[BCHUNK * 3];      // 45 rows x 12 floats
  __shared__ float cs[NC];
  __shared__ float wred[6];
  int bx = blockIdx.x;
  int r = bx >> 2, s = bx & 3;            // RSPLIT == 4
  int b0 = s * BCHUNK;
  int t = threadIdx.x;
  float* Hs = (float*)Hs4;
  if (bx == 0 && t == 0) {
    *(unsigned long long*)(wsf + WS_AKEY) = 0ULL;   // re-init angular argmax slots every call
    *(unsigned int*)(wsf + WS_ACNT) = 0u;
  }
  int ti = ((const int*)wsf)[WS_TYPEI];
  if (t < NC) cs[t] = wsf[WS_CXF + r * NC + t] + wsf[WS_CEM + ti * (NR * NC) + r * NC + t];
  __syncthreads();
  const float LOGM = -4.0482054576f;      // log(2*pi/360)
  for (int p = t; p < BCHUNK * 9; p += 384) {
    int b = p / 9, jj = p % 9;
    int bg = b0 + b;
    int n = c_h_cnt[jj];
    float acc = 0.f;
    for (int q = 0; q < n; q++) { int c = c_h_idx[jj][q]; acc += cs[c] * wsf[WS_Q + bg * NC + c]; }
    if (jj == 0) acc += logf(qw[bg]) + LOGM;   // fold log-measure into the m=0 term
    Hs[b * 12 + jj] = acc;
  }
  __syncthreads();
  float c1 = 0, c2 = 0, c3 = 0, c4 = 0, s1 = 0, s2 = 0, s3 = 0, s4 = 0;
  bool act = t < NA;
  if (act) {
    float al = alpha_grid[t];
    sincosf(al, &s1, &c1);
    sincosf(2.f * al, &s2, &c2);
    sincosf(3.f * al, &s3, &c3);
    sincosf(4.f * al, &s4, &c4);
  }
  float acc = 0.f;
#pragma unroll 5
  for (int b = 0; b < BCHUNK; b++) {
    float4 h0 = Hs4[b * 3 + 0], h1 = Hs4[b * 3 + 1], h2 = Hs4[b * 3 + 2];
    float f = h0.x + h0.y * c1 + h0.z * c2 + h0.w * c3 + h1.x * c4
            + h1.y * s1 + h1.z * s2 + h1.w * s3 + h2.x * s4;
    acc += act ? __expf(f) : 0.f;
  }
  for (int off = 32; off; off >>= 1) acc += __shfl_down(acc, off);
  int wid = t >> 6, lane = t & 63;
  if (lane == 0) wred[wid] = acc;
  __syncthreads();
  if (t == 0) {
    float ss = 0.f;
    for (int w = 0; w < 6; w++) ss += wred[w];
    wsf[WS_LRP + bx] = ss;
  }
}

// ---------------- K4: radial sample (redundant) + angular write + atomic argmax finish ----------------
__global__ __launch_bounds__(384) void k_ang(const float* __restrict__ qw,
    const float* __restrict__ alpha_grid, const float* __restrict__ y_grid,
    float* __restrict__ out, float* __restrict__ wsf) {
  __shared__ float wred[6]; __shared__ int wri[6];
  __shared__ float fss[NR];
  __shared__ float cs[NC];
  __shared__ float hsh[12];
  __shared__ float S_sh; __shared__ int r_sh;
  int b = blockIdx.x, t = threadIdx.x;
  int lane = t & 63, wid = t >> 6;
  const uint32_t* wu = (const uint32_t*)wsf;
  uint32_t kr0 = wu[WS_KEYS + 0], kr1 = wu[WS_KEYS + 1];
  uint32_t ka0 = wu[WS_KEYS + 2], ka1 = wu[WS_KEYS + 3];
  int ti = ((const int*)wsf)[WS_TYPEI];

  // ---- radial: every block computes the same sample (deterministic) ----
  float sv = 0.f, lr = -INFINITY;
  if (t < NR) {
    sv = wsf[WS_LRP + 4 * t] + wsf[WS_LRP + 4 * t + 1]
       + wsf[WS_LRP + 4 * t + 2] + wsf[WS_LRP + 4 * t + 3];
    fss[t] = sv;
    lr = logf(sv);
  }
  float ss = sv;
  for (int off = 32; off; off >>= 1) ss += __shfl_down(ss, off);
  if (lane == 0) wred[wid] = ss;
  __syncthreads();
  if (t == 0) {
    float S = 0.f;
    for (int w = 0; w < 6; w++) S += wred[w];
    S_sh = S;
  }
  __syncthreads();
  if (b == 0 && t < NR) out[O_RAD + t] = sv / S_sh;
  float v = (t < NR) ? lr + gumbel32(kr0, kr1, (uint32_t)t) : -INFINITY;
  int bi = (t < NR) ? t : (1 << 30);
  for (int off = 32; off; off >>= 1) {
    float v2 = __shfl_down(v, off); int i2 = __shfl_down(bi, off);
    if (v2 > v || (v2 == v && i2 < bi)) { v = v2; bi = i2; }
  }
  __syncthreads();
  if (lane == 0) { wred[wid] = v; wri[wid] = bi; }
  __syncthreads();
  if (t == 0) {
    float v0 = wred[0]; int i0 = wri[0];
    for (int w = 1; w < 6; w++)
      if (wred[w] > v0 || (wred[w] == v0 && wri[w] < i0)) { v0 = wred[w]; i0 = wri[w]; }
    r_sh = i0;
    if (b == 0) out[O_RADIUS] = (float)(i0 + 1) * 0.05f;
  }
  __syncthreads();
  int r = r_sh;
  float invZ = 1.0f / fss[r];             // Z_angular = exp(log_radial[r])

  // ---- coefficients + H for this beta ----
  if (t < NC) cs[t] = wsf[WS_CXF + r * NC + t] + wsf[WS_CEM + ti * (NR * NC) + r * NC + t];
  __syncthreads();
  if (t < 9) {
    int n = c_h_cnt[t];
    float acc = 0.f;
    for (int q = 0; q < n; q++) { int c = c_h_idx[t][q]; acc += cs[c] * wsf[WS_Q + b * NC + c]; }
    hsh[t] = acc;                         // no log-measure folded
  }
  __syncthreads();
  const float MEAS = 0.01745329252f;      // 2*pi/360
  float elm = qw[b] * MEAS;               // exp(log_meas[b]) exactly
  float lm = logf(elm);
  float va = -INFINITY; int idx = (t < NA) ? b * NA + t : (1 << 30);
  if (t < NA) {
    float al = alpha_grid[t];
    float s1, c1, s2, c2, s3, c3, s4, c4;
    sincosf(al, &s1, &c1); sincosf(2.f * al, &s2, &c2);
    sincosf(3.f * al, &s3, &c3); sincosf(4.f * al, &s4, &c4);
    float f = hsh[0] + hsh[1] * c1 + hsh[2] * c2 + hsh[3] * c3 + hsh[4] * c4
            + hsh[5] * s1 + hsh[6] * s2 + hsh[7] * s3 + hsh[8] * s4;
    out[O_ANG + idx] = __expf(f) * invZ;  // angular_dist = exp(fr - logZr)
    va = f + lm + gumbel32(ka0, ka1, (uint32_t)idx);
  }
  for (int off = 32; off; off >>= 1) {
    float v2 = __shfl_down(va, off); int i2 = __shfl_down(idx, off);
    if (v2 > va || (v2 == va && i2 < idx)) { va = v2; idx = i2; }
  }
  __syncthreads();
  if (lane == 0) { wred[wid] = va; wri[wid] = idx; }
  __syncthreads();
  if (t == 0) {
    float v0 = wred[0]; int i0 = wri[0];
    for (int w = 1; w < 6; w++)
      if (wred[w] > v0 || (wred[w] == v0 && wri[w] < i0)) { v0 = wred[w]; i0 = wri[w]; }
    // pack (value, index) into ordered u64: larger value wins; tie -> smaller index
    uint32_t u = __float_as_uint(v0);
    uint32_t ordv = (u & 0x80000000u) ? ~u : (u | 0x80000000u);
    unsigned long long key = ((unsigned long long)ordv << 32)
                           | (unsigned long long)(0xFFFFFFFFu - (uint32_t)i0);
    atomicMax((unsigned long long*)(wsf + WS_AKEY), key);
    __threadfence();
    unsigned int old = atomicAdd((unsigned int*)(wsf + WS_ACNT), 1u);
    if (old == NB - 1) {
      // last block: all 180 atomicMax ops are globally visible (release via fence+add chain)
      __threadfence();
      unsigned long long kk = atomicMax((unsigned long long*)(wsf + WS_AKEY), 0ULL);
      uint32_t gidx = 0xFFFFFFFFu - (uint32_t)(kk & 0xFFFFFFFFull);
      int yi = (int)(gidx / NA), ai = (int)(gidx % NA);
      out[O_Y] = y_grid[yi];
      out[O_ALPHA] = alpha_grid[ai];
    }
  }
}

// ---------------- launch ----------------
extern "C" void kernel_launch(void* const* d_in, const int* in_sizes, int n_in,
                              void* d_out, int out_size, void* d_ws, size_t ws_size,
                              hipStream_t stream) {
  const float* x          = (const float*)d_in[0];
  const float* fw1        = (const float*)d_in[1];
  const float* fw2        = (const float*)d_in[2];
  const float* fw3        = (const float*)d_in[3];
  const float* fw4        = (const float*)d_in[4];
  const float* fw5        = (const float*)d_in[5];
  const float* tw1        = (const float*)d_in[6];
  const float* tw2        = (const float*)d_in[7];
  const float* tw3        = (const float*)d_in[8];
  const float* tw4        = (const float*)d_in[9];
  const float* tw5        = (const float*)d_in[10];
  const float* tw6        = (const float*)d_in[11];
  const float* pos_w      = (const float*)d_in[12];
  const float* type_emb   = (const float*)d_in[13];
  const float* basis      = (const float*)d_in[14];
  const float* qw         = (const float*)d_in[15];
  const float* y_grid     = (const float*)d_in[16];
  const float* alpha_grid = (const float*)d_in[17];
  (void)in_sizes; (void)n_in; (void)out_size; (void)ws_size;
  float* out = (float*)d_out;
  float* wsf = (float*)d_ws;

  k_front<<<G1_TOTAL, 256, 0, stream>>>(x, fw1, fw2, fw3, fw4, fw5, basis, alpha_grid,
                                        tw1, tw2, tw3, tw4, tw5, tw6, pos_w, wsf);
  k_mid<<<1 + (NR * NC + 63) / 64, 1024, 0, stream>>>(x, tw1, tw2, tw3, tw4, tw5, tw6,
                                                      type_emb, pos_w, out, wsf);
  k_radial_lse<<<NR * RSPLIT, 384, 0, stream>>>(qw, alpha_grid, wsf);
  k_ang<<<NB, 384, 0, stream>>>(qw, alpha_grid, y_grid, out, wsf);
}

// Round 12
// 54.300 us; speedup vs baseline: 2.2867x; 1.0439x over previous
//
#include <hip/hip_runtime.h>
#include <math.h>
#include <stdint.h>

// ---------------- problem constants ----------------
#define NNODES 512
#define FEAT   128
#define NR     300
#define NC     25
#define NB     180
#define NA     360
#define RSPLIT 4
#define BCHUNK (NB / RSPLIT)   // 45
// output layout: type_dist[6] | radial_probs[300] | angular[64800] | radius | y | alpha
#define O_TYPE   0
#define O_RAD    6
#define O_ANG    306
#define O_RADIUS 65106
#define O_Y      65107
#define O_ALPHA  65108

// ---------------- workspace layout (float indices) ----------------
#define WS_KEYS   0     // 4 uints: k_r(2), k_a(2)
#define WS_TYPEI  5     // int
#define WS_DEAD   8     // dead slot for prefetch dummy-use
#define WS_SCORES 320   // 512
#define WS_PV     840   // 180
#define WS_PI     1020  // 180 ints
#define WS_Q      1664  // 180*25 = 4500
#define WS_CXF    6176  // 7500   xf-part of coeffs
#define WS_CEM    13696 // 5*7500 emb-part of coeffs per candidate type
#define WS_LRP    51200 // 300*RSPLIT partial sphere sums

// grid split for k_front (no pos_w prefetch: its consumers are BW-bound & parallel)
#define G1_MLP   64                      // 64 blocks x 8 nodes
#define G1_PREP  18                      // Q extraction (18*256 >= 4500)
#define G1_PFT   21                      // type-weight prefetch (k_mid block-0 is latency-bound)
#define G1_TOTAL (G1_MLP + G1_PREP + G1_PFT)   // 103

__constant__ int c_m_of_c[25] = {0,-1,0,1,-2,-1,0,1,2,-3,-2,-1,0,1,2,3,-4,-3,-2,-1,0,1,2,3,4};
__constant__ int c_h_cnt[9] = {5,4,3,2,1,4,3,2,1};
__constant__ int c_h_idx[9][5] = {
  {0,2,6,12,20},
  {3,7,13,21,0},
  {8,14,22,0,0},
  {15,23,0,0,0},
  {24,0,0,0,0},
  {1,5,11,19,0},
  {4,10,18,0,0},
  {9,17,0,0,0},
  {16,0,0,0,0}};

// ---------------- threefry2x32 (JAX semantics) ----------------
__device__ __forceinline__ void tf2x32(uint32_t k0, uint32_t k1, uint32_t x0, uint32_t x1,
                                       uint32_t& o0, uint32_t& o1) {
  uint32_t ks2 = k0 ^ k1 ^ 0x1BD11BDAu;
#define TF_RND(r) { x0 += x1; x1 = (x1 << r) | (x1 >> (32 - r)); x1 ^= x0; }
  x0 += k0; x1 += k1;
  TF_RND(13) TF_RND(15) TF_RND(26) TF_RND(6)
  x0 += k1; x1 += ks2 + 1u;
  TF_RND(17) TF_RND(29) TF_RND(16) TF_RND(24)
  x0 += ks2; x1 += k0 + 2u;
  TF_RND(13) TF_RND(15) TF_RND(26) TF_RND(6)
  x0 += k0; x1 += k1 + 3u;
  TF_RND(17) TF_RND(29) TF_RND(16) TF_RND(24)
  x0 += k1; x1 += ks2 + 4u;
  TF_RND(13) TF_RND(15) TF_RND(26) TF_RND(6)
  x0 += ks2; x1 += k0 + 5u;
#undef TF_RND
  o0 = x0; o1 = x1;
}

__device__ __forceinline__ float gumbel32(uint32_t k0, uint32_t k1, uint32_t lo) {
  uint32_t o0, o1; tf2x32(k0, k1, 0u, lo, o0, o1);
  uint32_t bits = o0 ^ o1;
  float u = __uint_as_float((bits >> 9) | 0x3f800000u) - 1.0f;   // [0,1)
  u = fmaxf(u, 1.1754944e-38f);                                   // minval = tiny
  return -logf(-logf(u));
}

__device__ __forceinline__ float softplusf(float s) {
  return fmaxf(s, 0.f) + log1pf(expf(-fabsf(s)));
}

// ---------------- K1: focus MLP + Q-prep + tw prefetch ----------------
__global__ __launch_bounds__(256) void k_front(const float* __restrict__ x,
    const float* __restrict__ w1, const float* __restrict__ w2, const float* __restrict__ w3,
    const float* __restrict__ w4, const float* __restrict__ w5,
    const float* __restrict__ basis, const float* __restrict__ alpha_grid,
    const float* __restrict__ tw1, const float* __restrict__ tw2, const float* __restrict__ tw3,
    const float* __restrict__ tw4, const float* __restrict__ tw5, const float* __restrict__ tw6,
    float* __restrict__ wsf) {
  __shared__ float A[8][128];
  __shared__ float B[8][128];
  int bx = blockIdx.x, t = threadIdx.x;

  if (bx < G1_MLP) {
    // ---- focus MLP: 8 nodes per block ----
    int base = bx * 8;
    for (int i = t; i < 8 * 128; i += 256) A[i >> 7][i & 127] = x[(base + (i >> 7)) * FEAT + (i & 127)];
    __syncthreads();
    int j = t & 127, h = t >> 7;          // h in {0,1}: nodes h*4..h*4+3
    {
      float a0 = 0, a1 = 0, a2 = 0, a3 = 0;
#pragma unroll 8
      for (int k = 0; k < 128; k++) {
        float wv = w1[k * 128 + j];
        a0 += A[h * 4 + 0][k] * wv; a1 += A[h * 4 + 1][k] * wv;
        a2 += A[h * 4 + 2][k] * wv; a3 += A[h * 4 + 3][k] * wv;
      }
      __syncthreads();
      B[h * 4 + 0][j] = fmaxf(a0, 0.f); B[h * 4 + 1][j] = fmaxf(a1, 0.f);
      B[h * 4 + 2][j] = fmaxf(a2, 0.f); B[h * 4 + 3][j] = fmaxf(a3, 0.f);
      __syncthreads();
    }
    {
      float a0 = 0, a1 = 0, a2 = 0, a3 = 0;
#pragma unroll 8
      for (int k = 0; k < 128; k++) {
        float wv = w2[k * 128 + j];
        a0 += B[h * 4 + 0][k] * wv; a1 += B[h * 4 + 1][k] * wv;
        a2 += B[h * 4 + 2][k] * wv; a3 += B[h * 4 + 3][k] * wv;
      }
      __syncthreads();
      A[h * 4 + 0][j] = fmaxf(a0, 0.f); A[h * 4 + 1][j] = fmaxf(a1, 0.f);
      A[h * 4 + 2][j] = fmaxf(a2, 0.f); A[h * 4 + 3][j] = fmaxf(a3, 0.f);
      __syncthreads();
    }
    {
      int j3 = t & 63, g = t >> 6;        // g in 0..3, nodes g*2, g*2+1
      float a0 = 0, a1 = 0;
#pragma unroll 8
      for (int k = 0; k < 128; k++) {
        float wv = w3[k * 64 + j3];
        a0 += A[g * 2 + 0][k] * wv; a1 += A[g * 2 + 1][k] * wv;
      }
      __syncthreads();
      B[g * 2 + 0][j3] = fmaxf(a0, 0.f); B[g * 2 + 1][j3] = fmaxf(a1, 0.f);
      __syncthreads();
    }
    {
      int j4 = t & 15, g4 = t >> 4;       // g4<8 -> node g4
      if (g4 < 8) {
        float a0 = 0;
#pragma unroll
        for (int k = 0; k < 64; k++) a0 += B[g4][k] * w4[k * 16 + j4];
        A[g4][j4] = fmaxf(a0, 0.f);
      }
      __syncthreads();
    }
    if (t < 8) {
      float a0 = 0;
#pragma unroll
      for (int k = 0; k < 16; k++) a0 += A[t][k] * w5[k * 2 + 0];
      wsf[WS_SCORES + base + t] = a0;
    }
  } else if (bx < G1_MLP + G1_PREP) {
    // ---- prep role: Q extraction + PRNG keys ----
    int p = (bx - G1_MLP) * 256 + t;
    if (bx == G1_MLP && t == 0) {
      uint32_t* wu = (uint32_t*)wsf;
      uint32_t o0, o1;
      tf2x32(0u, 42u, 0u, 0u, o0, o1); wu[WS_KEYS + 0] = o0; wu[WS_KEYS + 1] = o1; // k_r
      tf2x32(0u, 42u, 0u, 1u, o0, o1); wu[WS_KEYS + 2] = o0; wu[WS_KEYS + 3] = o1; // k_a
    }
    if (p < NB * NC) {
      int b = p / NC, c = p % NC;
      int m = c_m_of_c[c];
      float q;
      if (m >= 0) {
        q = basis[(b * NA + 0) * NC + c];                 // cos(0)=1
      } else {
        float a10 = alpha_grid[10];
        q = basis[(b * NA + 10) * NC + c] / sinf((float)(-m) * a10);
      }
      wsf[WS_Q + p] = q;
    }
  } else {
    // ---- type-weight prefetch into caches (for k_mid block-0's serial MLP) ----
    const float4* mats[5] = {(const float4*)tw1, (const float4*)tw2, (const float4*)tw3,
                             (const float4*)tw4, (const float4*)tw5};
    int lid = (bx - (G1_MLP + G1_PREP)) * 256 + t;
    float acc = 0.f;
    for (int vi = lid; vi < 20672; vi += G1_PFT * 256) {
      int mi = vi >> 12;
      float4 v;
      if (mi < 5) v = mats[mi][vi & 4095];
      else        v = ((const float4*)tw6)[vi - 20480];
      acc += v.x + v.y + v.z + v.w;
    }
    if (acc == -1.2345678e30f) wsf[WS_DEAD] = acc;   // never true; defeats DCE
  }
}

// ---------------- K2: block 0 = type MLP; blocks 1..118 = coeff parts (xf + 5 emb) ----------------
__global__ __launch_bounds__(1024) void k_mid(const float* __restrict__ x,
    const float* __restrict__ w1, const float* __restrict__ w2, const float* __restrict__ w3,
    const float* __restrict__ w4, const float* __restrict__ w5, const float* __restrict__ w6,
    const float* __restrict__ type_emb, const float* __restrict__ pos_w,
    float* __restrict__ out, float* __restrict__ wsf) {
  __shared__ float wrv[16]; __shared__ int wri[16];
  __shared__ int f_sh;
  int t = threadIdx.x;
  int lane = t & 63, wid = t >> 6;
  // ---- every block: focus argmax over 513 (scores ++ [0]) ----
  float bv = -INFINITY; int bi = 1 << 30;
  if (t < NNODES + 1) { bv = (t < NNODES) ? wsf[WS_SCORES + t] : 0.f; bi = t; }
  for (int off = 32; off; off >>= 1) {
    float v2 = __shfl_down(bv, off); int i2 = __shfl_down(bi, off);
    if (v2 > bv || (v2 == bv && i2 < bi)) { bv = v2; bi = i2; }
  }
  if (lane == 0) { wrv[wid] = bv; wri[wid] = bi; }
  __syncthreads();
  if (t == 0) {
    float v0 = wrv[0]; int i0 = wri[0];
    for (int w = 1; w < 16; w++)
      if (wrv[w] > v0 || (wrv[w] == v0 && wri[w] < i0)) { v0 = wrv[w]; i0 = wri[w]; }
    f_sh = (i0 < NNODES - 1) ? i0 : (NNODES - 1);
  }
  __syncthreads();
  int focus = f_sh;

  if (blockIdx.x == 0) {
    // ---- type MLP (softplus), K split 8 ways ----
    __shared__ float src[128];
    __shared__ float partial[8][128];
    if (t < 128) src[t] = x[focus * FEAT + t];
    __syncthreads();
    const float* Ws[5] = {w1, w2, w3, w4, w5};
#pragma unroll
    for (int L = 0; L < 5; L++) {
      const float* W = Ws[L];
      int j = t & 127, kc = t >> 7;
      float acc = 0.f;
#pragma unroll
      for (int k = 0; k < 16; k++) acc += src[kc * 16 + k] * W[(kc * 16 + k) * 128 + j];
      partial[kc][j] = acc;
      __syncthreads();
      if (t < 128) {
        float s = 0.f;
#pragma unroll
        for (int q = 0; q < 8; q++) s += partial[q][t];
        src[t] = softplusf(s);
      }
      __syncthreads();
    }
    float prod = 0.f;
    if (t < 768) { int o = t >> 7, j = t & 127; prod = src[j] * w6[j * 6 + o]; }
    for (int off = 32; off; off >>= 1) prod += __shfl_down(prod, off);
    if (t < 768 && lane == 0) wrv[wid] = prod;    // wid = 2*o (+1)
    __syncthreads();
    if (t == 0) {
      float lg[6];
      for (int o = 0; o < 6; o++) lg[o] = wrv[2 * o] + wrv[2 * o + 1];
      float M = lg[0]; int am = 0;
      for (int i = 1; i < 6; i++) if (lg[i] > M) { M = lg[i]; am = i; }
      float e[6], S = 0.f;
      for (int i = 0; i < 6; i++) { e[i] = expf(lg[i] - M); S += e[i]; }
      for (int i = 0; i < 6; i++) out[O_TYPE + i] = e[i] / S;
      ((int*)wsf)[WS_TYPEI] = (am < 4) ? am : 4;
    }
  } else {
    // ---- coefficient parts for 64 outputs ----
    __shared__ float xf[128];
    __shared__ float es[5 * 128];
    __shared__ float px[16][64];
    __shared__ float pe[5][16][64];
    if (t < 128) xf[t] = x[focus * FEAT + t];
    if (t < 640) es[t] = type_emb[t];
    __syncthreads();
    int oL = t & 63, kc = t >> 6;           // kc in 0..15
    int o = (blockIdx.x - 1) * 64 + oL;
    bool valid = o < NR * NC;
    float ax = 0.f, e0 = 0.f, e1 = 0.f, e2 = 0.f, e3 = 0.f, e4 = 0.f;
    if (valid) {
#pragma unroll
      for (int k8 = 0; k8 < 8; k8++) {
        int k = kc * 8 + k8;
        float w0 = pos_w[k * (NR * NC) + o];
        ax += xf[k] * w0;
        float wv = pos_w[(128 + k) * (NR * NC) + o];
        e0 += es[k] * wv;        e1 += es[128 + k] * wv;
        e2 += es[256 + k] * wv;  e3 += es[384 + k] * wv;
        e4 += es[512 + k] * wv;
      }
    }
    px[kc][oL] = ax;
    pe[0][kc][oL] = e0; pe[1][kc][oL] = e1; pe[2][kc][oL] = e2;
    pe[3][kc][oL] = e3; pe[4][kc][oL] = e4;
    __syncthreads();
    if (t < 64) {
      int oo = (blockIdx.x - 1) * 64 + t;
      if (oo < NR * NC) {
        float s = 0.f;
#pragma unroll
        for (int q = 0; q < 16; q++) s += px[q][t];
        wsf[WS_CXF + oo] = s;
#pragma unroll
        for (int ti = 0; ti < 5; ti++) {
          float s2 = 0.f;
#pragma unroll
          for (int q = 0; q < 16; q++) s2 += pe[ti][q][t];
          wsf[WS_CEM + ti * (NR * NC) + oo] = s2;
        }
      }
    }
  }
}

// ---------------- K3: per-(radius, beta-chunk) partial sphere sum (exp2-folded) ----------------
__global__ __launch_bounds__(384) void k_radial_lse(const float* __restrict__ qw,
    const float* __restrict__ alpha_grid, float* __restrict__ wsf) {
  __shared__ float4 Hs4[BCHUNK * 3];      // 45 rows x 12 floats
  __shared__ float cs[NC];
  __shared__ float wred[6];
  int bx = blockIdx.x;
  int r = bx >> 2, s = bx & 3;            // RSPLIT == 4
  int b0 = s * BCHUNK;
  int t = threadIdx.x;
  float* Hs = (float*)Hs4;
  int ti = ((const int*)wsf)[WS_TYPEI];
  if (t < NC) cs[t] = wsf[WS_CXF + r * NC + t] + wsf[WS_CEM + ti * (NR * NC) + r * NC + t];
  __syncthreads();
  const float LOGM = -4.0482054576f;      // log(2*pi/360)
  const float LOG2E = 1.44269504089f;
  for (int p = t; p < BCHUNK * 9; p += 384) {
    int b = p / 9, jj = p % 9;
    int bg = b0 + b;
    int n = c_h_cnt[jj];
    float acc = 0.f;
    for (int q = 0; q < n; q++) { int c = c_h_idx[jj][q]; acc += cs[c] * wsf[WS_Q + bg * NC + c]; }
    if (jj == 0) acc += logf(qw[bg]) + LOGM;   // fold log-measure into the m=0 term
    Hs[b * 12 + jj] = acc * LOG2E;             // pre-scale so the hot loop uses exp2
  }
  __syncthreads();
  float c1 = 0, c2 = 0, c3 = 0, c4 = 0, s1 = 0, s2 = 0, s3 = 0, s4 = 0;
  bool act = t < NA;
  if (act) {
    float al = alpha_grid[t];
    sincosf(al, &s1, &c1);
    sincosf(2.f * al, &s2, &c2);
    sincosf(3.f * al, &s3, &c3);
    sincosf(4.f * al, &s4, &c4);
  }
  float acc = 0.f;
#pragma unroll 5
  for (int b = 0; b < BCHUNK; b++) {
    float4 h0 = Hs4[b * 3 + 0], h1 = Hs4[b * 3 + 1], h2 = Hs4[b * 3 + 2];
    float f = h0.x + h0.y * c1 + h0.z * c2 + h0.w * c3 + h1.x * c4
            + h1.y * s1 + h1.z * s2 + h1.w * s3 + h2.x * s4;
    acc += act ? exp2f(f) : 0.f;               // native v_exp_f32
  }
  for (int off = 32; off; off >>= 1) acc += __shfl_down(acc, off);
  int wid = t >> 6, lane = t & 63;
  if (lane == 0) wred[wid] = acc;
  __syncthreads();
  if (t == 0) {
    float ss = 0.f;
    for (int w = 0; w < 6; w++) ss += wred[w];
    wsf[WS_LRP + bx] = ss;
  }
}

// ---------------- K4: radial sample (redundant) + normalized angular + partial argmax ----------------
__global__ __launch_bounds__(384) void k_ang(const float* __restrict__ qw,
    const float* __restrict__ alpha_grid, float* __restrict__ out, float* __restrict__ wsf) {
  __shared__ float wred[6]; __shared__ int wri[6];
  __shared__ float fss[NR];
  __shared__ float cs[NC];
  __shared__ float hsh[12];
  __shared__ float S_sh; __shared__ int r_sh;
  int b = blockIdx.x, t = threadIdx.x;
  int lane = t & 63, wid = t >> 6;
  const uint32_t* wu = (const uint32_t*)wsf;
  uint32_t kr0 = wu[WS_KEYS + 0], kr1 = wu[WS_KEYS + 1];
  uint32_t ka0 = wu[WS_KEYS + 2], ka1 = wu[WS_KEYS + 3];
  int ti = ((const int*)wsf)[WS_TYPEI];

  // ---- radial: every block computes the same sample (deterministic) ----
  float sv = 0.f, lr = -INFINITY;
  if (t < NR) {
    sv = wsf[WS_LRP + 4 * t] + wsf[WS_LRP + 4 * t + 1]
       + wsf[WS_LRP + 4 * t + 2] + wsf[WS_LRP + 4 * t + 3];
    fss[t] = sv;
    lr = logf(sv);
  }
  float ss = sv;
  for (int off = 32; off; off >>= 1) ss += __shfl_down(ss, off);
  if (lane == 0) wred[wid] = ss;
  __syncthreads();
  if (t == 0) {
    float S = 0.f;
    for (int w = 0; w < 6; w++) S += wred[w];
    S_sh = S;
  }
  __syncthreads();
  if (b == 0 && t < NR) out[O_RAD + t] = sv / S_sh;
  float v = (t < NR) ? lr + gumbel32(kr0, kr1, (uint32_t)t) : -INFINITY;
  int bi = (t < NR) ? t : (1 << 30);
  for (int off = 32; off; off >>= 1) {
    float v2 = __shfl_down(v, off); int i2 = __shfl_down(bi, off);
    if (v2 > v || (v2 == v && i2 < bi)) { v = v2; bi = i2; }
  }
  __syncthreads();
  if (lane == 0) { wred[wid] = v; wri[wid] = bi; }
  __syncthreads();
  if (t == 0) {
    float v0 = wred[0]; int i0 = wri[0];
    for (int w = 1; w < 6; w++)
      if (wred[w] > v0 || (wred[w] == v0 && wri[w] < i0)) { v0 = wred[w]; i0 = wri[w]; }
    r_sh = i0;
    if (b == 0) out[O_RADIUS] = (float)(i0 + 1) * 0.05f;
  }
  __syncthreads();
  int r = r_sh;
  float invZ = 1.0f / fss[r];             // Z_angular = exp(log_radial[r])

  // ---- coefficients + H for this beta ----
  if (t < NC) cs[t] = wsf[WS_CXF + r * NC + t] + wsf[WS_CEM + ti * (NR * NC) + r * NC + t];
  __syncthreads();
  if (t < 9) {
    int n = c_h_cnt[t];
    float acc = 0.f;
    for (int q = 0; q < n; q++) { int c = c_h_idx[t][q]; acc += cs[c] * wsf[WS_Q + b * NC + c]; }
    hsh[t] = acc;                         // no log-measure folded
  }
  __syncthreads();
  const float MEAS = 0.01745329252f;      // 2*pi/360
  float elm = qw[b] * MEAS;               // exp(log_meas[b]) exactly
  float lm = logf(elm);
  float va = -INFINITY; int idx = (t < NA) ? b * NA + t : (1 << 30);
  if (t < NA) {
    float al = alpha_grid[t];
    float s1, c1, s2, c2, s3, c3, s4, c4;
    sincosf(al, &s1, &c1); sincosf(2.f * al, &s2, &c2);
    sincosf(3.f * al, &s3, &c3); sincosf(4.f * al, &s4, &c4);
    float f = hsh[0] + hsh[1] * c1 + hsh[2] * c2 + hsh[3] * c3 + hsh[4] * c4
            + hsh[5] * s1 + hsh[6] * s2 + hsh[7] * s3 + hsh[8] * s4;
    out[O_ANG + idx] = __expf(f) * invZ;  // angular_dist = exp(fr - logZr)
    va = f + lm + gumbel32(ka0, ka1, (uint32_t)idx);
  }
  for (int off = 32; off; off >>= 1) {
    float v2 = __shfl_down(va, off); int i2 = __shfl_down(idx, off);
    if (v2 > va || (v2 == va && i2 < idx)) { va = v2; idx = i2; }
  }
  __syncthreads();
  if (lane == 0) { wred[wid] = va; wri[wid] = idx; }
  __syncthreads();
  if (t == 0) {
    float v0 = wred[0]; int i0 = wri[0];
    for (int w = 1; w < 6; w++)
      if (wred[w] > v0 || (wred[w] == v0 && wri[w] < i0)) { v0 = wred[w]; i0 = wri[w]; }
    wsf[WS_PV + b] = v0;
    ((int*)wsf)[WS_PI + b] = i0;
  }
}

// ---------------- K5: final angular argmax -> y/alpha outputs ----------------
__global__ __launch_bounds__(256) void k_ang_final(const float* __restrict__ y_grid,
    const float* __restrict__ alpha_grid, float* __restrict__ out, float* __restrict__ wsf) {
  __shared__ float wr[4]; __shared__ int wi[4];
  int t = threadIdx.x, lane = t & 63, wid = t >> 6;
  float v = (t < NB) ? wsf[WS_PV + t] : -INFINITY;
  int i = (t < NB) ? ((const int*)wsf)[WS_PI + t] : (1 << 30);
  for (int off = 32; off; off >>= 1) {
    float v2 = __shfl_down(v, off); int i2 = __shfl_down(i, off);
    if (v2 > v || (v2 == v && i2 < i)) { v = v2; i = i2; }
  }
  if (lane == 0) { wr[wid] = v; wi[wid] = i; }
  __syncthreads();
  if (t == 0) {
    float v0 = wr[0]; int i0 = wi[0];
    for (int w = 1; w < 4; w++)
      if (wr[w] > v0 || (wr[w] == v0 && wi[w] < i0)) { v0 = wr[w]; i0 = wi[w]; }
    int yi = i0 / NA, ai = i0 % NA;
    out[O_Y] = y_grid[yi];
    out[O_ALPHA] = alpha_grid[ai];
  }
}

// ---------------- launch ----------------
extern "C" void kernel_launch(void* const* d_in, const int* in_sizes, int n_in,
                              void* d_out, int out_size, void* d_ws, size_t ws_size,
                              hipStream_t stream) {
  const float* x          = (const float*)d_in[0];
  const float* fw1        = (const float*)d_in[1];
  const float* fw2        = (const float*)d_in[2];
  const float* fw3        = (const float*)d_in[3];
  const float* fw4        = (const float*)d_in[4];
  const float* fw5        = (const float*)d_in[5];
  const float* tw1        = (const float*)d_in[6];
  const float* tw2        = (const float*)d_in[7];
  const float* tw3        = (const float*)d_in[8];
  const float* tw4        = (const float*)d_in[9];
  const float* tw5        = (const float*)d_in[10];
  const float* tw6        = (const float*)d_in[11];
  const float* pos_w      = (const float*)d_in[12];
  const float* type_emb   = (const float*)d_in[13];
  const float* basis      = (const float*)d_in[14];
  const float* qw         = (const float*)d_in[15];
  const float* y_grid     = (const float*)d_in[16];
  const float* alpha_grid = (const float*)d_in[17];
  (void)in_sizes; (void)n_in; (void)out_size; (void)ws_size;
  float* out = (float*)d_out;
  float* wsf = (float*)d_ws;

  k_front<<<G1_TOTAL, 256, 0, stream>>>(x, fw1, fw2, fw3, fw4, fw5, basis, alpha_grid,
                                        tw1, tw2, tw3, tw4, tw5, tw6, wsf);
  k_mid<<<1 + (NR * NC + 63) / 64, 1024, 0, stream>>>(x, tw1, tw2, tw3, tw4, tw5, tw6,
                                                      type_emb, pos_w, out, wsf);
  k_radial_lse<<<NR * RSPLIT, 384, 0, stream>>>(qw, alpha_grid, wsf);
  k_ang<<<NB, 384, 0, stream>>>(qw, alpha_grid, out, wsf);
  k_ang_final<<<1, 256, 0, stream>>>(y_grid, alpha_grid, out, wsf);
}